// Round 1
// baseline (47.826 us; speedup 1.0000x reference)
//
#include <hip/hip_runtime.h>
#include <stdint.h>
#include <string.h>

// JAX >= 0.4.36 defaults jax_threefry_partitionable=True (counter = (0, i),
// output = w0 ^ w1). Set to 0 to fall back to the original layout
// (counts split in halves, w0 for low half / w1 for high half).
#define JAX_THREEFRY_PARTITIONABLE 1

#define DIN 100
#define DHID 512
#define DOUT 200
#define NPATH_AGG 5
#define NFINAL 10
#define MAXLEN 4
#define NSLOT (MAXLEN * NFINAL)      // 40 final (t, walk) slots
#define NENT (MAXLEN * NPATH_AGG)    // 20 visited entries per needed node

struct RngConsts {
  uint32_t kA[3][2];        // fold_in(fold_in(key(42),0), j), j=0..2
  int      starts2[NFINAL]; // jax.random.randint(fold_in(kw,1),(10,),0,N)
  float    u2[3][NFINAL];   // uniforms for the 10 final walks, steps 0..2
  int      N, maxd_bi, maxd_dir;
};

// ---------------- Threefry-2x32 (20 rounds), exactly as in jax._src.prng ---
__host__ __device__ inline void tf2x32(uint32_t k0, uint32_t k1,
                                       uint32_t& x0, uint32_t& x1) {
  const uint32_t k2 = k0 ^ k1 ^ 0x1BD11BDAu;
  x0 += k0; x1 += k1;
#define TFR(r) { x0 += x1; x1 = (x1 << (r)) | (x1 >> (32 - (r))); x1 ^= x0; }
  TFR(13) TFR(15) TFR(26) TFR(6)
  x0 += k1; x1 += k2 + 1u;
  TFR(17) TFR(29) TFR(16) TFR(24)
  x0 += k2; x1 += k0 + 2u;
  TFR(13) TFR(15) TFR(26) TFR(6)
  x0 += k0; x1 += k1 + 3u;
  TFR(17) TFR(29) TFR(16) TFR(24)
  x0 += k1; x1 += k2 + 4u;
  TFR(13) TFR(15) TFR(26) TFR(6)
  x0 += k2; x1 += k0 + 5u;
#undef TFR
}

// random_bits(key, 32, (size,)) element idx; half = size/2 (size even here).
__host__ __device__ inline uint32_t jax_bits32(uint32_t k0, uint32_t k1,
                                               uint32_t idx, uint32_t half) {
#if JAX_THREEFRY_PARTITIONABLE
  (void)half;
  uint32_t x0 = 0u, x1 = idx;   // 64-bit counter i -> (hi, lo) = (0, i)
  tf2x32(k0, k1, x0, x1);
  return x0 ^ x1;               // 32-bit fold of the 64-bit block output
#else
  uint32_t x0, x1;
  const bool lo = idx < half;
  if (lo) { x0 = idx;        x1 = idx + half; }
  else    { x0 = idx - half; x1 = idx;        }
  tf2x32(k0, k1, x0, x1);
  return lo ? x0 : x1;
#endif
}

// jax.random.uniform: bitcast((bits>>9) | 0x3F800000) - 1.0
__host__ __device__ inline float bits_to_unif(uint32_t bits) {
  uint32_t f = (bits >> 9) | 0x3F800000u;
  float r;
  memcpy(&r, &f, 4);
  return r - 1.0f;
}

// ---------------- Kernel 1: the 10 final directed walks --------------------
__global__ void k_final_walks(const int* __restrict__ nbr_dir,
                              const int* __restrict__ deg_dir,
                              RngConsts rc,
                              int* __restrict__ nodes2,
                              int* __restrict__ masks2) {
  int i = threadIdx.x;
  if (i >= NFINAL) return;
  int cur = rc.starts2[i];
  int valid = 1;
  nodes2[0 * NFINAL + i] = cur;
  masks2[0 * NFINAL + i] = 1;
  for (int j = 0; j < MAXLEN - 1; ++j) {
    int d = deg_dir[cur];
    float u = rc.u2[j][i];
    int c = (int)(u * (float)d);
    int cm = (d - 1 > 0) ? d - 1 : 0;
    if (c > cm) c = cm;
    valid = valid && (d > 0);
    if (valid) cur = nbr_dir[(long long)cur * rc.maxd_dir + c];
    nodes2[(j + 1) * NFINAL + i] = cur;
    masks2[(j + 1) * NFINAL + i] = valid;
  }
}

// ---------------- Kernel 2: per-slot agg-walks + fc1 + mean + fc3 ----------
__global__ __launch_bounds__(DHID) void k_slot(
    const float* __restrict__ x,
    const int* __restrict__ nbr_bi, const int* __restrict__ deg_bi,
    const float* __restrict__ W1, const float* __restrict__ b1,
    const float* __restrict__ W3, const float* __restrict__ b3,
    const int* __restrict__ nodes2, const int* __restrict__ masks2,
    RngConsts rc, float* __restrict__ out2v /* [NSLOT][DOUT] */) {
  __shared__ int   vnode[NENT];
  __shared__ int   vmask[NENT];
  __shared__ float xs[NENT][DIN];
  __shared__ float aggv[DHID];
  __shared__ float cnt_s;

  const int slot = blockIdx.x;
  if (masks2[slot] == 0) return;          // uniform across block
  const int n = nodes2[slot];
  const int tid = threadIdx.x;

  // 5 aggregation walks from node n; walker id w = p*N + n (starts1 tiling).
  if (tid < NPATH_AGG) {
    const int p = tid;
    const uint32_t w = (uint32_t)(p * rc.N + n);
    int cur = n, valid = 1;
    vnode[0 * NPATH_AGG + p] = cur;
    vmask[0 * NPATH_AGG + p] = 1;
    for (int j = 0; j < MAXLEN - 1; ++j) {
      const float u = bits_to_unif(
          jax_bits32(rc.kA[j][0], rc.kA[j][1], w, 250000u));
      const int d = deg_bi[cur];
      int c = (int)(u * (float)d);
      const int cm = (d - 1 > 0) ? d - 1 : 0;
      if (c > cm) c = cm;
      valid = valid && (d > 0);
      if (valid) cur = nbr_bi[(long long)cur * rc.maxd_bi + c];
      vnode[(j + 1) * NPATH_AGG + p] = cur;
      vmask[(j + 1) * NPATH_AGG + p] = valid;
    }
  }
  __syncthreads();

  // Stage the (<=20) visited x rows into LDS; compute count.
  for (int idx = tid; idx < NENT * DIN; idx += blockDim.x) {
    const int e = idx / DIN, k = idx % DIN;
    xs[e][k] = x[(long long)vnode[e] * DIN + k];
  }
  if (tid == 0) {
    int c = 0;
    for (int e = 0; e < NENT; ++e) c += vmask[e];
    cnt_s = (float)c;
  }
  __syncthreads();

  // Hidden unit tid: agg[tid] = mean over masked entries of relu(x[v].W1[tid]+b1)
  {
    float acc[NENT];
#pragma unroll
    for (int e = 0; e < NENT; ++e) acc[e] = 0.0f;
    const float* wrow = W1 + (long long)tid * DIN;
    for (int k = 0; k < DIN; ++k) {
      const float wv = wrow[k];
#pragma unroll
      for (int e = 0; e < NENT; ++e) acc[e] += xs[e][k] * wv;
    }
    const float bb = b1[tid];
    float hsum = 0.0f;
    for (int e = 0; e < NENT; ++e) {
      if (vmask[e]) {
        const float hv = acc[e] + bb;
        hsum += (hv > 0.0f) ? hv : 0.0f;
      }
    }
    aggv[tid] = hsum / cnt_s;
  }
  __syncthreads();

  // Output unit tid (<200): out2 row = relu(agg . W3[tid] + b3[tid])
  if (tid < DOUT) {
    const float* wrow = W3 + (long long)tid * DHID;
    float dot = b3[tid];
    for (int k = 0; k < DHID; ++k) dot += aggv[k] * wrow[k];
    out2v[slot * DOUT + tid] = (dot > 0.0f) ? dot : 0.0f;
  }
}

// ---------------- Kernel 3: deterministic masked mean ----------------------
__global__ void k_final(const float* __restrict__ out2v,
                        const int* __restrict__ masks2,
                        float* __restrict__ out) {
  const int o = threadIdx.x;
  if (o >= DOUT) return;
  float s = 0.0f, ws = 0.0f;
  for (int slot = 0; slot < NSLOT; ++slot) {
    if (masks2[slot]) { s += out2v[slot * DOUT + o]; ws += 1.0f; }
  }
  out[o] = s / ws;
}

// ---------------- Host-side PRNG chain -------------------------------------
static void h_enc(const uint32_t k[2], uint32_t x0, uint32_t x1, uint32_t out[2]) {
  tf2x32(k[0], k[1], x0, x1);
  out[0] = x0; out[1] = x1;
}
static void h_foldin(const uint32_t k[2], uint32_t data, uint32_t out[2]) {
  // fold_in(key, d) = threefry_2x32(key, seed(d)) with seed(d) = (0, d)
  h_enc(k, 0u, data, out);
}

extern "C" void kernel_launch(void* const* d_in, const int* in_sizes, int n_in,
                              void* d_out, int out_size, void* d_ws, size_t ws_size,
                              hipStream_t stream) {
  const float* x       = (const float*)d_in[0];
  const int*   nbr_bi  = (const int*)d_in[2];
  const int*   deg_bi  = (const int*)d_in[3];
  const int*   nbr_dir = (const int*)d_in[4];
  const int*   deg_dir = (const int*)d_in[5];
  const float* W1      = (const float*)d_in[6];
  const float* b1      = (const float*)d_in[7];
  const float* W3      = (const float*)d_in[8];
  const float* b3      = (const float*)d_in[9];

  const int N = in_sizes[0] / DIN;
  RngConsts rc;
  rc.N = N;
  rc.maxd_bi  = in_sizes[2] / N;
  rc.maxd_dir = in_sizes[4] / N;

  const uint32_t kw[2] = {0u, 42u};            // jax.random.key(42)
  uint32_t kA[2];
  h_foldin(kw, 0u, kA);                        // agg-walk base key
  for (uint32_t j = 0; j < 3; ++j) h_foldin(kA, j, rc.kA[j]);

  // starts2 = randint(fold_in(kw,1), (10,), 0, N, int32)
  uint32_t kS[2];
  h_foldin(kw, 1u, kS);
  uint32_t k1_[2], k2_[2];
#if JAX_THREEFRY_PARTITIONABLE
  h_enc(kS, 0u, 0u, k1_);                      // foldlike split: enc(0, i)
  h_enc(kS, 0u, 1u, k2_);
#else
  {
    uint32_t a[2], b[2];                       // counts [0,1,2,3] -> (0,2),(1,3)
    h_enc(kS, 0u, 2u, a);
    h_enc(kS, 1u, 3u, b);
    k1_[0] = a[0]; k1_[1] = b[0];
    k2_[0] = a[1]; k2_[1] = b[1];
  }
#endif
  {
    const uint32_t span = (uint32_t)N;
    uint32_t mult = 65536u % span;
    mult = (uint32_t)(mult * mult) % span;     // uint32 wrap, exactly like lax.mul
    for (uint32_t i = 0; i < NFINAL; ++i) {
      const uint32_t hi = jax_bits32(k1_[0], k1_[1], i, NFINAL / 2);
      const uint32_t lo = jax_bits32(k2_[0], k2_[1], i, NFINAL / 2);
      uint32_t off = (hi % span) * mult + (lo % span);  // uint32 wrap
      off %= span;
      rc.starts2[i] = (int)off;
    }
  }

  // Final-walk uniforms: key fold_in(kw,2), steps j=0..2, shape (10,)
  uint32_t kP[2];
  h_foldin(kw, 2u, kP);
  for (uint32_t j = 0; j < 3; ++j) {
    uint32_t kPj[2];
    h_foldin(kP, j, kPj);
    for (uint32_t i = 0; i < NFINAL; ++i)
      rc.u2[j][i] = bits_to_unif(jax_bits32(kPj[0], kPj[1], i, NFINAL / 2));
  }

  // Workspace layout: nodes2[40] | masks2[40] | out2v[40*200]
  int*   nodes2 = (int*)d_ws;
  int*   masks2 = nodes2 + NSLOT;
  float* out2v  = (float*)(masks2 + NSLOT);

  k_final_walks<<<1, 64, 0, stream>>>(nbr_dir, deg_dir, rc, nodes2, masks2);
  k_slot<<<NSLOT, DHID, 0, stream>>>(x, nbr_bi, deg_bi, W1, b1, W3, b3,
                                     nodes2, masks2, rc, out2v);
  k_final<<<1, 256, 0, stream>>>(out2v, masks2, (float*)d_out);
}